// Round 4
// baseline (263.581 us; speedup 1.0000x reference)
//
#include <hip/hip_runtime.h>
#include <stdint.h>

#define EPS_NORM 1e-8
#define EPS_Q 1e-5

typedef int v4i __attribute__((ext_vector_type(4)));

__device__ __forceinline__ double wave_sum_d(double v) {
#pragma unroll
  for (int o = 32; o; o >>= 1) v += __shfl_xor(v, o);
  return v;
}
__device__ __forceinline__ float wave_max(float v) {
#pragma unroll
  for (int o = 32; o; o >>= 1) v = fmaxf(v, __shfl_xor(v, o));
  return v;
}

// ---------------- weight |w| sum (both tensors), fp64 accumulation ----------------
__global__ void wabs_sum_kernel(const float* __restrict__ w1,
                                const float* __restrict__ w2,
                                double* __restrict__ sums) {
  const float4* w = (const float4*)(blockIdx.y ? w2 : w1);
  const int n4 = 4194304 / 4;
  double s = 0.0;
  for (int i = blockIdx.x * blockDim.x + threadIdx.x; i < n4;
       i += gridDim.x * blockDim.x) {
    float4 t = w[i];
    s += (double)fabsf(t.x) + (double)fabsf(t.y) + (double)fabsf(t.z) +
         (double)fabsf(t.w);
  }
  s = wave_sum_d(s);
  __shared__ double red[4];
  const int wid = threadIdx.x >> 6;
  if ((threadIdx.x & 63) == 0) red[wid] = s;
  __syncthreads();
  if (threadIdx.x == 0)
    atomicAdd(&sums[blockIdx.y], red[0] + red[1] + red[2] + red[3]);
}

// ---------------- ternary weight quant (fp64 scale+round): q=clip(rint(w*s),-1,1) ----------------
__global__ void wquant_kernel(const float* __restrict__ w, int8_t* __restrict__ q,
                              const double* __restrict__ sum, double ninv) {
  const double s = 1.0 / fmax(sum[0] * ninv, EPS_Q);
  const int i = blockIdx.x * blockDim.x + threadIdx.x;
  float4 t = ((const float4*)w)[i];
  int a = (int)rint((double)t.x * s); a = a < -1 ? -1 : (a > 1 ? 1 : a);
  int b = (int)rint((double)t.y * s); b = b < -1 ? -1 : (b > 1 ? 1 : b);
  int c = (int)rint((double)t.z * s); c = c < -1 ? -1 : (c > 1 ? 1 : c);
  int d = (int)rint((double)t.w * s); d = d < -1 ? -1 : (d > 1 ? 1 : d);
  ((int*)q)[i] = (a & 255) | ((b & 255) << 8) | ((c & 255) << 16) | ((d & 255) << 24);
}

// ------------- rmsnorm + per-token 8-bit quant (one block per token) -------------
// fp64 sum-of-squares + rsqrt; multiply order matches reference: (x*rs)*w.
template <int D>
__global__ __launch_bounds__(256) void rq_kernel(
    const float* __restrict__ X, const float* __restrict__ W,
    int8_t* __restrict__ Q, float* __restrict__ recips) {
  constexpr int C = D / 1024;  // float4 chunks per thread (256 threads)
  const int t = blockIdx.x;
  const int tid = threadIdx.x;
  const int wid = tid >> 6;
  const int lane = tid & 63;
  const float4* xr = (const float4*)(X + (size_t)t * D);
  const float4* wr = (const float4*)W;
  float4 xv[C];
  double ss = 0.0;
#pragma unroll
  for (int c = 0; c < C; ++c) {
    xv[c] = xr[c * 256 + tid];
    ss += (double)xv[c].x * xv[c].x + (double)xv[c].y * xv[c].y +
          (double)xv[c].z * xv[c].z + (double)xv[c].w * xv[c].w;
  }
  ss = wave_sum_d(ss);
  __shared__ double reds[4];
  __shared__ float redm[4];
  if (lane == 0) reds[wid] = ss;
  __syncthreads();
  const double v = (reds[0] + reds[1] + reds[2] + reds[3]) * (1.0 / (double)D);
  const float rs = (float)(1.0 / sqrt(v + EPS_NORM));
  float am = 0.f;
#pragma unroll
  for (int c = 0; c < C; ++c) {
    float4 wv = wr[c * 256 + tid];
    xv[c].x = (xv[c].x * rs) * wv.x;
    xv[c].y = (xv[c].y * rs) * wv.y;
    xv[c].z = (xv[c].z * rs) * wv.z;
    xv[c].w = (xv[c].w * rs) * wv.w;
    am = fmaxf(am, fmaxf(fmaxf(fabsf(xv[c].x), fabsf(xv[c].y)),
                         fmaxf(fabsf(xv[c].z), fabsf(xv[c].w))));
  }
  am = wave_max(am);
  if (lane == 0) redm[wid] = am;
  __syncthreads();
  am = fmaxf(fmaxf(redm[0], redm[1]), fmaxf(redm[2], redm[3]));
  am = fmaxf(am, 1e-5f);
  const float scale = 127.f / am;
  int8_t* qrow = Q + (size_t)t * D;
#pragma unroll
  for (int c = 0; c < C; ++c) {
    int q0 = (int)rintf(xv[c].x * scale); q0 = q0 < -128 ? -128 : (q0 > 127 ? 127 : q0);
    int q1 = (int)rintf(xv[c].y * scale); q1 = q1 < -128 ? -128 : (q1 > 127 ? 127 : q1);
    int q2 = (int)rintf(xv[c].z * scale); q2 = q2 < -128 ? -128 : (q2 > 127 ? 127 : q2);
    int q3 = (int)rintf(xv[c].w * scale); q3 = q3 < -128 ? -128 : (q3 > 127 ? 127 : q3);
    ((int*)qrow)[c * 256 + tid] =
        (q0 & 255) | ((q1 & 255) << 8) | ((q2 & 255) << 16) | ((q3 & 255) << 24);
  }
  if (tid == 0) recips[t] = am * (1.f / 127.f);
}

// ---------------- int8 GEMM: C[M,N] = A[M,K] x B[N,K]^T, fused dequant ----------------
// 128x128 tile, BK=128, 4 waves (2x2), per-wave 64x64 out via 4x4 frags of 16x16x64 i8.
// global_load_lds width-16 staging with XOR-swizzled per-lane *global* source
// (LDS stays linear), swizzled ds_read_b128 -> ~2-way bank conflicts.
template <bool STAR>
__global__ __launch_bounds__(256) void gemm_i8_kernel(
    const int8_t* __restrict__ A, const int8_t* __restrict__ B,
    float* __restrict__ C, int N, int K, const float* __restrict__ tokrecip,
    const double* __restrict__ wsum, double wninv,
    const float* __restrict__ sa_p, const float* __restrict__ sb_p) {
  __shared__ int8_t smem[32768];
  int8_t* As = smem;
  int8_t* Bs = smem + 16384;
  const int tid = threadIdx.x;
  const int lane = tid & 63;
  const int wid = tid >> 6;
  const int n0 = blockIdx.x * 128;
  const int t0 = blockIdx.y * 128;

  // staging map: thread covers LDS bytes (j*4096 + tid*16); row=j*32+tid/8
  const int srow = tid >> 3;                       // 0..31
  const int scol = ((tid & 7) ^ (srow & 7)) << 4;  // pre-swizzled global col
  const int8_t* Ag = A + (size_t)(t0 + srow) * K + scol;
  const int8_t* Bg = B + (size_t)(n0 + srow) * K + scol;

  v4i acc[4][4];
  v4i zero = {0, 0, 0, 0};
#pragma unroll
  for (int m = 0; m < 4; ++m)
#pragma unroll
    for (int n = 0; n < 4; ++n) acc[m][n] = zero;

  const int wr = (wid >> 1) << 6;   // wave row offset in tile
  const int wc = (wid & 1) << 6;    // wave col offset in tile
  const int fr = lane & 15;         // fragment row
  const int fk = (lane >> 4) << 4;  // k-chunk byte offset (16B per lane group)

  for (int k0 = 0; k0 < K; k0 += 128) {
#pragma unroll
    for (int j = 0; j < 4; ++j) {
      __builtin_amdgcn_global_load_lds(
          (const __attribute__((address_space(1))) void*)(Ag + (size_t)(j * 32) * K + k0),
          (__attribute__((address_space(3))) void*)(As + j * 4096 + wid * 1024),
          16, 0, 0);
      __builtin_amdgcn_global_load_lds(
          (const __attribute__((address_space(1))) void*)(Bg + (size_t)(j * 32) * K + k0),
          (__attribute__((address_space(3))) void*)(Bs + j * 4096 + wid * 1024),
          16, 0, 0);
    }
    __syncthreads();
#pragma unroll
    for (int kk = 0; kk < 2; ++kk) {
      v4i a[4], b[4];
#pragma unroll
      for (int m = 0; m < 4; ++m) {
        const int row = wr + m * 16 + fr;
        const int col = (kk * 64 + fk) ^ ((row & 7) << 4);
        a[m] = *(const v4i*)(As + row * 128 + col);
      }
#pragma unroll
      for (int n = 0; n < 4; ++n) {
        const int row = wc + n * 16 + fr;
        const int col = (kk * 64 + fk) ^ ((row & 7) << 4);
        b[n] = *(const v4i*)(Bs + row * 128 + col);
      }
#pragma unroll
      for (int m = 0; m < 4; ++m)
#pragma unroll
        for (int n = 0; n < 4; ++n)
          acc[m][n] = __builtin_amdgcn_mfma_i32_16x16x64_i8(a[m], b[n], acc[m][n], 0, 0, 0);
    }
    __syncthreads();
  }

  // epilogue: dequant (+ StarReLU for layer 1)
  const float wrecip = (float)fmax(wsum[0] * wninv, EPS_Q);
  float sa = 0.f, sb = 0.f;
  if (STAR) { sa = sa_p[0]; sb = sb_p[0]; }
  const int r0 = t0 + wr + ((lane >> 4) << 2);  // C/D: row=(lane>>4)*4+reg
  const int c0 = n0 + wc + (lane & 15);         // C/D: col=lane&15
#pragma unroll
  for (int m = 0; m < 4; ++m) {
    float tr[4];
#pragma unroll
    for (int r = 0; r < 4; ++r) tr[r] = tokrecip[r0 + m * 16 + r] * wrecip;
#pragma unroll
    for (int n = 0; n < 4; ++n) {
#pragma unroll
      for (int r = 0; r < 4; ++r) {
        float f = (float)acc[m][n][r] * tr[r];
        if (STAR) {
          const float rl = fmaxf(f, 0.f);
          f = fmaf(sa, rl * rl, sb);
        }
        C[(size_t)(r0 + m * 16 + r) * N + (c0 + n * 16)] = f;
      }
    }
  }
}

extern "C" void kernel_launch(void* const* d_in, const int* in_sizes, int n_in,
                              void* d_out, int out_size, void* d_ws, size_t ws_size,
                              hipStream_t stream) {
  const float* x    = (const float*)d_in[0];  // [4,2048,1024]
  const float* n1w  = (const float*)d_in[1];  // [1024]
  const float* w1   = (const float*)d_in[2];  // [4096,1024]
  const float* as_p = (const float*)d_in[3];  // [1]
  const float* ab_p = (const float*)d_in[4];  // [1]
  const float* n2w  = (const float*)d_in[5];  // [4096]
  const float* w2   = (const float*)d_in[6];  // [1024,4096]
  float* out = (float*)d_out;                 // [4,2048,1024]

  char* ws = (char*)d_ws;
  float*  h   = (float*)ws;                      // 8192*4096 f32 = 128 MiB
  int8_t* x1q = (int8_t*)(ws + 134217728ULL);    // 8 MiB  [dead after gemm1]
  int8_t* x2q = (int8_t*)(ws + 134217728ULL);    // 32 MiB [reuses x1q region]
  int8_t* w1q = (int8_t*)(ws + 167772160ULL);    // 4 MiB
  int8_t* w2q = (int8_t*)(ws + 171966464ULL);    // 4 MiB
  float*  tr1 = (float*)(ws + 176160768ULL);     // 8192 f32
  float*  tr2 = (float*)(ws + 176193536ULL);     // 8192 f32
  double* sums = (double*)(ws + 176226304ULL);   // 2 f64 (|w1| sum, |w2| sum)

  hipMemsetAsync(sums, 0, 2 * sizeof(double), stream);
  wabs_sum_kernel<<<dim3(512, 2), 256, 0, stream>>>(w1, w2, sums);
  wquant_kernel<<<4096, 256, 0, stream>>>(w1, w1q, sums + 0, 1.0 / 4194304.0);
  wquant_kernel<<<4096, 256, 0, stream>>>(w2, w2q, sums + 1, 1.0 / 4194304.0);
  rq_kernel<1024><<<8192, 256, 0, stream>>>(x, n1w, x1q, tr1);
  gemm_i8_kernel<true><<<dim3(32, 64), 256, 0, stream>>>(
      x1q, w1q, h, 4096, 1024, tr1, sums + 0, 1.0 / 4194304.0, as_p, ab_p);
  rq_kernel<4096><<<8192, 256, 0, stream>>>(h, n2w, x2q, tr2);
  gemm_i8_kernel<false><<<dim3(8, 64), 256, 0, stream>>>(
      x2q, w2q, out, 1024, 4096, tr2, sums + 1, 1.0 / 4194304.0, nullptr, nullptr);
}

// Round 15
// 250.969 us; speedup vs baseline: 1.0503x; 1.0503x over previous
//
#include <hip/hip_runtime.h>
#include <stdint.h>

#define EPS_NORM 1e-8
#define EPS_Q 1e-5

typedef int v4i __attribute__((ext_vector_type(4)));

__device__ __forceinline__ double wave_sum_d(double v) {
#pragma unroll
  for (int o = 32; o; o >>= 1) v += __shfl_xor(v, o);
  return v;
}
__device__ __forceinline__ float wave_max(float v) {
#pragma unroll
  for (int o = 32; o; o >>= 1) v = fmaxf(v, __shfl_xor(v, o));
  return v;
}

// ------- weight |w| partial sums: partials[tensor*512+block], no atomics -------
__global__ void wabs_sum_kernel(const float* __restrict__ w1,
                                const float* __restrict__ w2,
                                double* __restrict__ partials) {
  const float4* w = (const float4*)(blockIdx.y ? w2 : w1);
  const int n4 = 4194304 / 4;
  double s = 0.0;
  for (int i = blockIdx.x * blockDim.x + threadIdx.x; i < n4;
       i += gridDim.x * blockDim.x) {
    float4 t = w[i];
    s += (double)fabsf(t.x) + (double)fabsf(t.y) + (double)fabsf(t.z) +
         (double)fabsf(t.w);
  }
  s = wave_sum_d(s);
  __shared__ double red[4];
  const int wid = threadIdx.x >> 6;
  if ((threadIdx.x & 63) == 0) red[wid] = s;
  __syncthreads();
  if (threadIdx.x == 0)
    partials[blockIdx.y * 512 + blockIdx.x] = red[0] + red[1] + red[2] + red[3];
}

// ------- ternary quant, both tensors (grid.y selects), reduces partials itself -------
__global__ void wquant_kernel(const float* __restrict__ w1,
                              const float* __restrict__ w2,
                              int8_t* __restrict__ q1, int8_t* __restrict__ q2,
                              const double* __restrict__ partials) {
  const int tz = blockIdx.y;
  const float* w = tz ? w2 : w1;
  int8_t* q = tz ? q2 : q1;
  double s = partials[tz * 512 + threadIdx.x] + partials[tz * 512 + 256 + threadIdx.x];
  s = wave_sum_d(s);
  __shared__ double red[4];
  if ((threadIdx.x & 63) == 0) red[threadIdx.x >> 6] = s;
  __syncthreads();
  const double total = red[0] + red[1] + red[2] + red[3];
  const double sc = 1.0 / fmax(total * (1.0 / 4194304.0), EPS_Q);
  const int i = blockIdx.x * blockDim.x + threadIdx.x;
  float4 t = ((const float4*)w)[i];
  int a = (int)rint((double)t.x * sc); a = a < -1 ? -1 : (a > 1 ? 1 : a);
  int b = (int)rint((double)t.y * sc); b = b < -1 ? -1 : (b > 1 ? 1 : b);
  int c = (int)rint((double)t.z * sc); c = c < -1 ? -1 : (c > 1 ? 1 : c);
  int d = (int)rint((double)t.w * sc); d = d < -1 ? -1 : (d > 1 ? 1 : d);
  ((int*)q)[i] = (a & 255) | ((b & 255) << 8) | ((c & 255) << 16) | ((d & 255) << 24);
}

// ------------- rmsnorm + per-token 8-bit quant (one block per token) -------------
template <int D>
__global__ __launch_bounds__(256) void rq_kernel(
    const float* __restrict__ X, const float* __restrict__ W,
    int8_t* __restrict__ Q, float* __restrict__ recips) {
  constexpr int C = D / 1024;
  const int t = blockIdx.x;
  const int tid = threadIdx.x;
  const int wid = tid >> 6;
  const int lane = tid & 63;
  const float4* xr = (const float4*)(X + (size_t)t * D);
  const float4* wr = (const float4*)W;
  float4 xv[C];
  double ss = 0.0;
#pragma unroll
  for (int c = 0; c < C; ++c) {
    xv[c] = xr[c * 256 + tid];
    ss += (double)xv[c].x * xv[c].x + (double)xv[c].y * xv[c].y +
          (double)xv[c].z * xv[c].z + (double)xv[c].w * xv[c].w;
  }
  ss = wave_sum_d(ss);
  __shared__ double reds[4];
  __shared__ float redm[4];
  if (lane == 0) reds[wid] = ss;
  __syncthreads();
  const double v = (reds[0] + reds[1] + reds[2] + reds[3]) * (1.0 / (double)D);
  const float rs = (float)(1.0 / sqrt(v + EPS_NORM));
  float am = 0.f;
#pragma unroll
  for (int c = 0; c < C; ++c) {
    float4 wv = wr[c * 256 + tid];
    xv[c].x = (xv[c].x * rs) * wv.x;
    xv[c].y = (xv[c].y * rs) * wv.y;
    xv[c].z = (xv[c].z * rs) * wv.z;
    xv[c].w = (xv[c].w * rs) * wv.w;
    am = fmaxf(am, fmaxf(fmaxf(fabsf(xv[c].x), fabsf(xv[c].y)),
                         fmaxf(fabsf(xv[c].z), fabsf(xv[c].w))));
  }
  am = wave_max(am);
  if (lane == 0) redm[wid] = am;
  __syncthreads();
  am = fmaxf(fmaxf(redm[0], redm[1]), fmaxf(redm[2], redm[3]));
  am = fmaxf(am, 1e-5f);
  const float scale = 127.f / am;
  int8_t* qrow = Q + (size_t)t * D;
#pragma unroll
  for (int c = 0; c < C; ++c) {
    int q0 = (int)rintf(xv[c].x * scale); q0 = q0 < -128 ? -128 : (q0 > 127 ? 127 : q0);
    int q1 = (int)rintf(xv[c].y * scale); q1 = q1 < -128 ? -128 : (q1 > 127 ? 127 : q1);
    int q2 = (int)rintf(xv[c].z * scale); q2 = q2 < -128 ? -128 : (q2 > 127 ? 127 : q2);
    int q3 = (int)rintf(xv[c].w * scale); q3 = q3 < -128 ? -128 : (q3 > 127 ? 127 : q3);
    ((int*)qrow)[c * 256 + tid] =
        (q0 & 255) | ((q1 & 255) << 8) | ((q2 & 255) << 16) | ((q3 & 255) << 24);
  }
  if (tid == 0) recips[t] = am * (1.f / 127.f);
}

// ---------------- int8 GEMM: C[M,N] = A[M,K] x B[N,K]^T, fused dequant ----------------
// Block tile (MF*32) x (NF*32), BK=128, 4 waves (2x2); per-wave MFx NF frags of 16x16x64.
// global_load_lds width-16 staging, XOR-swizzled per-lane *global* source (LDS linear),
// swizzled ds_read_b128 -> conflict-free (verified: SQ_LDS_BANK_CONFLICT=0).
template <int MF, int NF, bool STAR>
__global__ __launch_bounds__(256) void gemm_i8_kernel(
    const int8_t* __restrict__ A, const int8_t* __restrict__ B,
    float* __restrict__ C, int N, int K, const float* __restrict__ tokrecip,
    const double* __restrict__ partials, double wninv,
    const float* __restrict__ sa_p, const float* __restrict__ sb_p) {
  constexpr int MT = MF * 32;  // block rows (tokens)
  constexpr int NT = NF * 32;  // block cols
  __shared__ int8_t smem[(MT + NT) * 128];
  int8_t* As = smem;
  int8_t* Bs = smem + MT * 128;
  const int tid = threadIdx.x;
  const int lane = tid & 63;
  const int wid = tid >> 6;
  const int n0 = blockIdx.x * NT;
  const int t0 = blockIdx.y * MT;

  // weight scale from partials (tiny redundant reduce, L2-hot)
  double wsum = 0.0;
#pragma unroll 8
  for (int i = lane; i < 512; i += 64) wsum += partials[i + (STAR ? 0 : 512)];
  wsum = wave_sum_d(wsum);
  const float wrecip = (float)fmax(wsum * wninv, EPS_Q);

  // staging map: wave w covers LDS bytes [j*4096 + w*1024, +1024); row=j*32+tid/8
  const int srow = tid >> 3;                       // 0..31
  const int scol = ((tid & 7) ^ (srow & 7)) << 4;  // pre-swizzled global col
  const int8_t* Ag = A + (size_t)(t0 + srow) * K + scol;
  const int8_t* Bg = B + (size_t)(n0 + srow) * K + scol;

  v4i acc[MF][NF];
  v4i zero = {0, 0, 0, 0};
#pragma unroll
  for (int m = 0; m < MF; ++m)
#pragma unroll
    for (int n = 0; n < NF; ++n) acc[m][n] = zero;

  const int wr = (wid >> 1) * (MF * 16);  // wave row offset
  const int wc = (wid & 1) * (NF * 16);   // wave col offset
  const int fr = lane & 15;               // fragment row
  const int fk = (lane >> 4) << 4;        // k-chunk byte offset

  for (int k0 = 0; k0 < K; k0 += 128) {
#pragma unroll
    for (int j = 0; j < MF; ++j)
      __builtin_amdgcn_global_load_lds(
          (const __attribute__((address_space(1))) void*)(Ag + (size_t)(j * 32) * K + k0),
          (__attribute__((address_space(3))) void*)(As + j * 4096 + wid * 1024),
          16, 0, 0);
#pragma unroll
    for (int j = 0; j < NF; ++j)
      __builtin_amdgcn_global_load_lds(
          (const __attribute__((address_space(1))) void*)(Bg + (size_t)(j * 32) * K + k0),
          (__attribute__((address_space(3))) void*)(Bs + j * 4096 + wid * 1024),
          16, 0, 0);
    __syncthreads();
#pragma unroll
    for (int kk = 0; kk < 2; ++kk) {
      v4i a[MF], b[NF];
#pragma unroll
      for (int m = 0; m < MF; ++m) {
        const int row = wr + m * 16 + fr;
        const int col = (kk * 64 + fk) ^ ((row & 7) << 4);
        a[m] = *(const v4i*)(As + row * 128 + col);
      }
#pragma unroll
      for (int n = 0; n < NF; ++n) {
        const int row = wc + n * 16 + fr;
        const int col = (kk * 64 + fk) ^ ((row & 7) << 4);
        b[n] = *(const v4i*)(Bs + row * 128 + col);
      }
#pragma unroll
      for (int m = 0; m < MF; ++m)
#pragma unroll
        for (int n = 0; n < NF; ++n)
          acc[m][n] = __builtin_amdgcn_mfma_i32_16x16x64_i8(a[m], b[n], acc[m][n], 0, 0, 0);
    }
    __syncthreads();
  }

  // epilogue: dequant (+ StarReLU for layer 1)
  float sa = 0.f, sb = 0.f;
  if (STAR) { sa = sa_p[0]; sb = sb_p[0]; }
  const int r0 = t0 + wr + ((lane >> 4) << 2);  // C/D: row=(lane>>4)*4+reg
  const int c0 = n0 + wc + (lane & 15);         // C/D: col=lane&15
#pragma unroll
  for (int m = 0; m < MF; ++m) {
    float tr[4];
#pragma unroll
    for (int r = 0; r < 4; ++r) tr[r] = tokrecip[r0 + m * 16 + r] * wrecip;
#pragma unroll
    for (int n = 0; n < NF; ++n) {
#pragma unroll
      for (int r = 0; r < 4; ++r) {
        float f = (float)acc[m][n][r] * tr[r];
        if (STAR) {
          const float rl = fmaxf(f, 0.f);
          f = fmaf(sa, rl * rl, sb);
        }
        C[(size_t)(r0 + m * 16 + r) * N + (c0 + n * 16)] = f;
      }
    }
  }
}

extern "C" void kernel_launch(void* const* d_in, const int* in_sizes, int n_in,
                              void* d_out, int out_size, void* d_ws, size_t ws_size,
                              hipStream_t stream) {
  const float* x    = (const float*)d_in[0];  // [4,2048,1024]
  const float* n1w  = (const float*)d_in[1];  // [1024]
  const float* w1   = (const float*)d_in[2];  // [4096,1024]
  const float* as_p = (const float*)d_in[3];  // [1]
  const float* ab_p = (const float*)d_in[4];  // [1]
  const float* n2w  = (const float*)d_in[5];  // [4096]
  const float* w2   = (const float*)d_in[6];  // [1024,4096]
  float* out = (float*)d_out;                 // [4,2048,1024]

  char* ws = (char*)d_ws;
  float*  h   = (float*)ws;                      // 8192*4096 f32 = 128 MiB
  int8_t* x1q = (int8_t*)(ws + 134217728ULL);    // 8 MiB  [dead after gemm1]
  int8_t* x2q = (int8_t*)(ws + 134217728ULL);    // 32 MiB [reuses x1q region]
  int8_t* w1q = (int8_t*)(ws + 167772160ULL);    // 4 MiB
  int8_t* w2q = (int8_t*)(ws + 171966464ULL);    // 4 MiB
  float*  tr1 = (float*)(ws + 176160768ULL);     // 8192 f32
  float*  tr2 = (float*)(ws + 176193536ULL);     // 8192 f32
  double* partials = (double*)(ws + 176226304ULL); // 1024 f64 partial |w| sums

  wabs_sum_kernel<<<dim3(512, 2), 256, 0, stream>>>(w1, w2, partials);
  wquant_kernel<<<dim3(4096, 2), 256, 0, stream>>>(w1, w2, w1q, w2q, partials);
  rq_kernel<1024><<<8192, 256, 0, stream>>>(x, n1w, x1q, tr1);
  gemm_i8_kernel<4, 4, true><<<dim3(32, 64), 256, 0, stream>>>(
      x1q, w1q, h, 4096, 1024, tr1, partials, 1.0 / 4194304.0, as_p, ab_p);
  rq_kernel<4096><<<8192, 256, 0, stream>>>(h, n2w, x2q, tr2);
  gemm_i8_kernel<4, 2, false><<<dim3(16, 64), 256, 0, stream>>>(
      x2q, w2q, out, 1024, 4096, tr2, partials, 1.0 / 4194304.0, nullptr, nullptr);
}

// Round 16
// 234.710 us; speedup vs baseline: 1.1230x; 1.0693x over previous
//
#include <hip/hip_runtime.h>
#include <stdint.h>

#define EPS_NORM 1e-8
#define EPS_Q 1e-5

typedef int v4i __attribute__((ext_vector_type(4)));
typedef short s8v __attribute__((ext_vector_type(8)));

__device__ __forceinline__ double wave_sum_d(double v) {
#pragma unroll
  for (int o = 32; o; o >>= 1) v += __shfl_xor(v, o);
  return v;
}
__device__ __forceinline__ float wave_max(float v) {
#pragma unroll
  for (int o = 32; o; o >>= 1) v = fmaxf(v, __shfl_xor(v, o));
  return v;
}

// ------- weight |w| partial sums: partials[tensor*512+block], no atomics -------
__global__ void wabs_sum_kernel(const float* __restrict__ w1,
                                const float* __restrict__ w2,
                                double* __restrict__ partials) {
  const float4* w = (const float4*)(blockIdx.y ? w2 : w1);
  const int n4 = 4194304 / 4;
  double s = 0.0;
  for (int i = blockIdx.x * blockDim.x + threadIdx.x; i < n4;
       i += gridDim.x * blockDim.x) {
    float4 t = w[i];
    s += (double)fabsf(t.x) + (double)fabsf(t.y) + (double)fabsf(t.z) +
         (double)fabsf(t.w);
  }
  s = wave_sum_d(s);
  __shared__ double red[4];
  const int wid = threadIdx.x >> 6;
  if ((threadIdx.x & 63) == 0) red[wid] = s;
  __syncthreads();
  if (threadIdx.x == 0)
    partials[blockIdx.y * 512 + blockIdx.x] = red[0] + red[1] + red[2] + red[3];
}

// ------- ternary quant, both tensors (grid.y selects), reduces partials itself -------
__global__ void wquant_kernel(const float* __restrict__ w1,
                              const float* __restrict__ w2,
                              int8_t* __restrict__ q1, int8_t* __restrict__ q2,
                              const double* __restrict__ partials) {
  const int tz = blockIdx.y;
  const float* w = tz ? w2 : w1;
  int8_t* q = tz ? q2 : q1;
  double s = partials[tz * 512 + threadIdx.x] + partials[tz * 512 + 256 + threadIdx.x];
  s = wave_sum_d(s);
  __shared__ double red[4];
  if ((threadIdx.x & 63) == 0) red[threadIdx.x >> 6] = s;
  __syncthreads();
  const double total = red[0] + red[1] + red[2] + red[3];
  const double sc = 1.0 / fmax(total * (1.0 / 4194304.0), EPS_Q);
  const int i = blockIdx.x * blockDim.x + threadIdx.x;
  float4 t = ((const float4*)w)[i];
  int a = (int)rint((double)t.x * sc); a = a < -1 ? -1 : (a > 1 ? 1 : a);
  int b = (int)rint((double)t.y * sc); b = b < -1 ? -1 : (b > 1 ? 1 : b);
  int c = (int)rint((double)t.z * sc); c = c < -1 ? -1 : (c > 1 ? 1 : c);
  int d = (int)rint((double)t.w * sc); d = d < -1 ? -1 : (d > 1 ? 1 : d);
  ((int*)q)[i] = (a & 255) | ((b & 255) << 8) | ((c & 255) << 16) | ((d & 255) << 24);
}

// ------- rmsnorm + per-token 8-bit quant, f32 input (layer 1, D=1024) -------
__global__ __launch_bounds__(256) void rq1_kernel(
    const float* __restrict__ X, const float* __restrict__ W,
    int8_t* __restrict__ Q, float* __restrict__ recips) {
  const int t = blockIdx.x;
  const int tid = threadIdx.x;
  const int wid = tid >> 6;
  const int lane = tid & 63;
  float4 xv = ((const float4*)(X + (size_t)t * 1024))[tid];
  double ss = (double)xv.x * xv.x + (double)xv.y * xv.y +
              (double)xv.z * xv.z + (double)xv.w * xv.w;
  ss = wave_sum_d(ss);
  __shared__ double reds[4];
  __shared__ float redm[4];
  if (lane == 0) reds[wid] = ss;
  __syncthreads();
  const double v = (reds[0] + reds[1] + reds[2] + reds[3]) * (1.0 / 1024.0);
  const float rs = (float)(1.0 / sqrt(v + EPS_NORM));
  float4 wv = ((const float4*)W)[tid];
  xv.x = (xv.x * rs) * wv.x;
  xv.y = (xv.y * rs) * wv.y;
  xv.z = (xv.z * rs) * wv.z;
  xv.w = (xv.w * rs) * wv.w;
  float am = fmaxf(fmaxf(fabsf(xv.x), fabsf(xv.y)), fmaxf(fabsf(xv.z), fabsf(xv.w)));
  am = wave_max(am);
  if (lane == 0) redm[wid] = am;
  __syncthreads();
  am = fmaxf(fmaxf(redm[0], redm[1]), fmaxf(redm[2], redm[3]));
  am = fmaxf(am, 1e-5f);
  const float scale = 127.f / am;
  int q0 = (int)rintf(xv.x * scale); q0 = q0 < -128 ? -128 : (q0 > 127 ? 127 : q0);
  int q1 = (int)rintf(xv.y * scale); q1 = q1 < -128 ? -128 : (q1 > 127 ? 127 : q1);
  int q2 = (int)rintf(xv.z * scale); q2 = q2 < -128 ? -128 : (q2 > 127 ? 127 : q2);
  int q3 = (int)rintf(xv.w * scale); q3 = q3 < -128 ? -128 : (q3 > 127 ? 127 : q3);
  ((int*)(Q + (size_t)t * 1024))[tid] =
      (q0 & 255) | ((q1 & 255) << 8) | ((q2 & 255) << 16) | ((q3 & 255) << 24);
  if (tid == 0) recips[t] = am * (1.f / 127.f);
}

// ------- rmsnorm + per-token 8-bit quant, f16 input (layer 2, D=4096) -------
__global__ __launch_bounds__(256) void rq2_kernel(
    const _Float16* __restrict__ X, const float* __restrict__ W,
    int8_t* __restrict__ Q, float* __restrict__ recips) {
  const int t = blockIdx.x;
  const int tid = threadIdx.x;
  const int wid = tid >> 6;
  const int lane = tid & 63;
  const s8v* xr = (const s8v*)(X + (size_t)t * 4096);  // 8 halves / 16B
  float xf[16];
  double ss = 0.0;
#pragma unroll
  for (int c = 0; c < 2; ++c) {
    s8v hv = xr[c * 256 + tid];
#pragma unroll
    for (int j = 0; j < 8; ++j) {
      _Float16 hb;
      *(short*)&hb = hv[j];
      const float f = (float)hb;
      xf[c * 8 + j] = f;
      ss += (double)f * f;
    }
  }
  ss = wave_sum_d(ss);
  __shared__ double reds[4];
  __shared__ float redm[4];
  if (lane == 0) reds[wid] = ss;
  __syncthreads();
  const double v = (reds[0] + reds[1] + reds[2] + reds[3]) * (1.0 / 4096.0);
  const float rs = (float)(1.0 / sqrt(v + EPS_NORM));
  float am = 0.f;
#pragma unroll
  for (int c = 0; c < 2; ++c) {
    // W chunk for elements [c*2048 + tid*8, +8)
    const float4 w0 = *(const float4*)(W + c * 2048 + tid * 8);
    const float4 w1 = *(const float4*)(W + c * 2048 + tid * 8 + 4);
    xf[c * 8 + 0] = (xf[c * 8 + 0] * rs) * w0.x;
    xf[c * 8 + 1] = (xf[c * 8 + 1] * rs) * w0.y;
    xf[c * 8 + 2] = (xf[c * 8 + 2] * rs) * w0.z;
    xf[c * 8 + 3] = (xf[c * 8 + 3] * rs) * w0.w;
    xf[c * 8 + 4] = (xf[c * 8 + 4] * rs) * w1.x;
    xf[c * 8 + 5] = (xf[c * 8 + 5] * rs) * w1.y;
    xf[c * 8 + 6] = (xf[c * 8 + 6] * rs) * w1.z;
    xf[c * 8 + 7] = (xf[c * 8 + 7] * rs) * w1.w;
#pragma unroll
    for (int j = 0; j < 8; ++j) am = fmaxf(am, fabsf(xf[c * 8 + j]));
  }
  am = wave_max(am);
  if (lane == 0) redm[wid] = am;
  __syncthreads();
  am = fmaxf(fmaxf(redm[0], redm[1]), fmaxf(redm[2], redm[3]));
  am = fmaxf(am, 1e-5f);
  const float scale = 127.f / am;
  int8_t* qrow = Q + (size_t)t * 4096;
#pragma unroll
  for (int c = 0; c < 2; ++c) {
    int pk[2] = {0, 0};
#pragma unroll
    for (int j = 0; j < 8; ++j) {
      int q = (int)rintf(xf[c * 8 + j] * scale);
      q = q < -128 ? -128 : (q > 127 ? 127 : q);
      pk[j >> 2] |= (q & 255) << ((j & 3) * 8);
    }
    *(int2*)(qrow + c * 2048 + tid * 8) = make_int2(pk[0], pk[1]);
  }
  if (tid == 0) recips[t] = am * (1.f / 127.f);
}

// ---------------- int8 GEMM: C[M,N] = A[M,K] x B[N,K]^T, fused dequant ----------------
// Block tile (MF*32) x (NF*32), BK=128, 4 waves (2x2); per-wave MFx NF frags of 16x16x64.
// global_load_lds width-16 staging, XOR-swizzled per-lane *global* source (LDS linear),
// swizzled ds_read_b128 -> conflict-free (verified: SQ_LDS_BANK_CONFLICT=0).
// STAR=true: fused StarReLU epilogue, output _Float16; STAR=false: output f32.
template <int MF, int NF, bool STAR>
__global__ __launch_bounds__(256) void gemm_i8_kernel(
    const int8_t* __restrict__ A, const int8_t* __restrict__ B,
    void* __restrict__ C, int N, int K, const float* __restrict__ tokrecip,
    const double* __restrict__ partials, double wninv,
    const float* __restrict__ sa_p, const float* __restrict__ sb_p) {
  constexpr int MT = MF * 32;  // block rows (tokens)
  constexpr int NT = NF * 32;  // block cols
  __shared__ int8_t smem[(MT + NT) * 128];
  int8_t* As = smem;
  int8_t* Bs = smem + MT * 128;
  const int tid = threadIdx.x;
  const int lane = tid & 63;
  const int wid = tid >> 6;
  const int n0 = blockIdx.x * NT;
  const int t0 = blockIdx.y * MT;

  // weight scale from partials (tiny redundant reduce, L2-hot)
  double wsum = 0.0;
#pragma unroll 8
  for (int i = lane; i < 512; i += 64) wsum += partials[i + (STAR ? 0 : 512)];
  wsum = wave_sum_d(wsum);
  const float wrecip = (float)fmax(wsum * wninv, EPS_Q);

  // staging map: wave w covers LDS bytes [j*4096 + w*1024, +1024); row=j*32+tid/8
  const int srow = tid >> 3;                       // 0..31
  const int scol = ((tid & 7) ^ (srow & 7)) << 4;  // pre-swizzled global col
  const int8_t* Ag = A + (size_t)(t0 + srow) * K + scol;
  const int8_t* Bg = B + (size_t)(n0 + srow) * K + scol;

  v4i acc[MF][NF];
  v4i zero = {0, 0, 0, 0};
#pragma unroll
  for (int m = 0; m < MF; ++m)
#pragma unroll
    for (int n = 0; n < NF; ++n) acc[m][n] = zero;

  const int wr = (wid >> 1) * (MF * 16);  // wave row offset
  const int wc = (wid & 1) * (NF * 16);   // wave col offset
  const int fr = lane & 15;               // fragment row
  const int fk = (lane >> 4) << 4;        // k-chunk byte offset

  for (int k0 = 0; k0 < K; k0 += 128) {
#pragma unroll
    for (int j = 0; j < MF; ++j)
      __builtin_amdgcn_global_load_lds(
          (const __attribute__((address_space(1))) void*)(Ag + (size_t)(j * 32) * K + k0),
          (__attribute__((address_space(3))) void*)(As + j * 4096 + wid * 1024),
          16, 0, 0);
#pragma unroll
    for (int j = 0; j < NF; ++j)
      __builtin_amdgcn_global_load_lds(
          (const __attribute__((address_space(1))) void*)(Bg + (size_t)(j * 32) * K + k0),
          (__attribute__((address_space(3))) void*)(Bs + j * 4096 + wid * 1024),
          16, 0, 0);
    __syncthreads();
#pragma unroll
    for (int kk = 0; kk < 2; ++kk) {
      v4i a[MF], b[NF];
#pragma unroll
      for (int m = 0; m < MF; ++m) {
        const int row = wr + m * 16 + fr;
        const int col = (kk * 64 + fk) ^ ((row & 7) << 4);
        a[m] = *(const v4i*)(As + row * 128 + col);
      }
#pragma unroll
      for (int n = 0; n < NF; ++n) {
        const int row = wc + n * 16 + fr;
        const int col = (kk * 64 + fk) ^ ((row & 7) << 4);
        b[n] = *(const v4i*)(Bs + row * 128 + col);
      }
#pragma unroll
      for (int m = 0; m < MF; ++m)
#pragma unroll
        for (int n = 0; n < NF; ++n)
          acc[m][n] = __builtin_amdgcn_mfma_i32_16x16x64_i8(a[m], b[n], acc[m][n], 0, 0, 0);
    }
    __syncthreads();
  }

  // epilogue: dequant (+ StarReLU -> f16 for layer 1)
  float sa = 0.f, sb = 0.f;
  if (STAR) { sa = sa_p[0]; sb = sb_p[0]; }
  const int r0 = t0 + wr + ((lane >> 4) << 2);  // C/D: row=(lane>>4)*4+reg
  const int c0 = n0 + wc + (lane & 15);         // C/D: col=lane&15
#pragma unroll
  for (int m = 0; m < MF; ++m) {
    float tr[4];
#pragma unroll
    for (int r = 0; r < 4; ++r) tr[r] = tokrecip[r0 + m * 16 + r] * wrecip;
#pragma unroll
    for (int n = 0; n < NF; ++n) {
#pragma unroll
      for (int r = 0; r < 4; ++r) {
        float f = (float)acc[m][n][r] * tr[r];
        const size_t idx = (size_t)(r0 + m * 16 + r) * N + (c0 + n * 16);
        if (STAR) {
          const float rl = fmaxf(f, 0.f);
          f = fmaf(sa, rl * rl, sb);
          ((_Float16*)C)[idx] = (_Float16)f;
        } else {
          ((float*)C)[idx] = f;
        }
      }
    }
  }
}

extern "C" void kernel_launch(void* const* d_in, const int* in_sizes, int n_in,
                              void* d_out, int out_size, void* d_ws, size_t ws_size,
                              hipStream_t stream) {
  const float* x    = (const float*)d_in[0];  // [4,2048,1024]
  const float* n1w  = (const float*)d_in[1];  // [1024]
  const float* w1   = (const float*)d_in[2];  // [4096,1024]
  const float* as_p = (const float*)d_in[3];  // [1]
  const float* ab_p = (const float*)d_in[4];  // [1]
  const float* n2w  = (const float*)d_in[5];  // [4096]
  const float* w2   = (const float*)d_in[6];  // [1024,4096]
  float* out = (float*)d_out;                 // [4,2048,1024]

  char* ws = (char*)d_ws;
  _Float16* h = (_Float16*)ws;                   // 8192*4096 f16 = 64 MiB
  int8_t* x1q = (int8_t*)(ws + 134217728ULL);    // 8 MiB  [dead after gemm1]
  int8_t* x2q = (int8_t*)(ws + 134217728ULL);    // 32 MiB [reuses x1q region]
  int8_t* w1q = (int8_t*)(ws + 167772160ULL);    // 4 MiB
  int8_t* w2q = (int8_t*)(ws + 171966464ULL);    // 4 MiB
  float*  tr1 = (float*)(ws + 176160768ULL);     // 8192 f32
  float*  tr2 = (float*)(ws + 176193536ULL);     // 8192 f32
  double* partials = (double*)(ws + 176226304ULL); // 1024 f64 partial |w| sums

  wabs_sum_kernel<<<dim3(512, 2), 256, 0, stream>>>(w1, w2, partials);
  wquant_kernel<<<dim3(4096, 2), 256, 0, stream>>>(w1, w2, w1q, w2q, partials);
  rq1_kernel<<<8192, 256, 0, stream>>>(x, n1w, x1q, tr1);
  gemm_i8_kernel<4, 4, true><<<dim3(32, 64), 256, 0, stream>>>(
      x1q, w1q, h, 4096, 1024, tr1, partials, 1.0 / 4194304.0, as_p, ab_p);
  rq2_kernel<<<8192, 256, 0, stream>>>(h, n2w, x2q, tr2);
  gemm_i8_kernel<4, 2, false><<<dim3(16, 64), 256, 0, stream>>>(
      x2q, w2q, out, 1024, 4096, tr2, partials, 1.0 / 4194304.0, nullptr, nullptr);
}